// Round 5
// baseline (427.407 us; speedup 1.0000x reference)
//
#include <hip/hip_runtime.h>
#include <math.h>

constexpr int NN = 20000;   // nodes
constexpr int NE = 320000;  // edges
constexpr int MPAD = 20096; // NN padded to 128 (=> multiple of 64)

typedef __bf16 bf16x8 __attribute__((ext_vector_type(8)));
typedef float f32x4 __attribute__((ext_vector_type(4)));

__device__ __forceinline__ unsigned short f2bf(float f) {
  unsigned int u = __float_as_uint(f);
  unsigned int r = (u + 0x7FFFu + ((u >> 16) & 1u)) >> 16;
  return (unsigned short)r;
}
__device__ __forceinline__ float bf2f(unsigned short s) {
  return __uint_as_float(((unsigned int)s) << 16);
}

// ---------------- degree count ----------------
__global__ void deg_count_kernel(const int* __restrict__ src, const int* __restrict__ dst,
                                 int* __restrict__ degs, int* __restrict__ degd, int nE) {
  int e = blockIdx.x * blockDim.x + threadIdx.x;
  if (e < nE) {
    atomicAdd(degs + src[e], 1);
    atomicAdd(degd + dst[e], 1);
  }
}

__global__ void norm_kernel(const int* __restrict__ degs, const int* __restrict__ degd,
                            float* __restrict__ ns, float* __restrict__ nd, int n) {
  int i = blockIdx.x * blockDim.x + threadIdx.x;
  if (i < n) {
    ns[i] = rsqrtf(fmaxf((float)degs[i], 1.0f));
    nd[i] = rsqrtf(fmaxf((float)degd[i], 1.0f));
  }
}

// ---------------- single-block exclusive scan -> rowptr ----------------
__global__ __launch_bounds__(1024) void scan_kernel(const int* __restrict__ deg,
                                                    int* __restrict__ rowptr, int n) {
  constexpr int T = 1024;
  const int ITEMS = (n + T - 1) / T;
  __shared__ int sums[T];
  int t = threadIdx.x;
  int base = t * ITEMS;
  int s = 0;
  for (int i = 0; i < ITEMS; ++i) {
    int idx = base + i;
    if (idx < n) s += deg[idx];
  }
  sums[t] = s;
  __syncthreads();
  for (int off = 1; off < T; off <<= 1) {
    int v = (t >= off) ? sums[t - off] : 0;
    __syncthreads();
    sums[t] += v;
    __syncthreads();
  }
  int ex = (t == 0) ? 0 : sums[t - 1];
  for (int i = 0; i < ITEMS; ++i) {
    int idx = base + i;
    if (idx < n) {
      rowptr[idx] = ex;
      ex += deg[idx];
    }
  }
  if (t == 0) rowptr[n] = sums[T - 1];
}

// ---------------- CSR fill ----------------
__global__ void csr_fill_kernel(const int* __restrict__ src, const int* __restrict__ dst,
                                const int* __restrict__ rowptr, int* __restrict__ cursor,
                                int* __restrict__ col, int nE) {
  int e = blockIdx.x * blockDim.x + threadIdx.x;
  if (e < nE) {
    int d = dst[e];
    int p = atomicAdd(cursor + d, 1);
    col[rowptr[d] + p] = src[e];
  }
}

// ---------------- weight convert: W[K][N] f32 -> Wt[Npad][Kpad] bf16 (zero pad) -------
__global__ void wt_convert_kernel(const float* __restrict__ W, unsigned short* __restrict__ Wt,
                                  int K, int N, int Kpad) {
  int k = blockIdx.x * 256 + threadIdx.x;
  int n = blockIdx.y;
  if (k >= Kpad) return;
  float v = (n < N && k < K) ? W[(size_t)k * N + n] : 0.f;
  Wt[(size_t)n * Kpad + k] = f2bf(v);
}

// ---------------- CSR gather aggregation ----------------
// EPI==0: write raw sum. EPI==1: v=sum*sDst+b -> out(f32) AND sigmoid(v)->out2.
// EPI==2: v=sum*sDst+b -> sigmoid(v)->out2 only.
template <int F, int SCALE_SRC, int EPI, int OUT_BF, int IN_BF>
__global__ __launch_bounds__(256) void gather_kernel(
    const void* __restrict__ in, const float* __restrict__ sSrc,
    const int* __restrict__ rowptr, const int* __restrict__ col,
    const float* __restrict__ sDst, const float* __restrict__ bias,
    void* __restrict__ out, float* __restrict__ out2, int n) {
  constexpr int F4 = F / 4;
  constexpr int NPB = 256 / F4;
  int tid = threadIdx.x;
  int node = blockIdx.x * NPB + tid / F4;
  int j = tid % F4;
  if (node >= n) return;
  int e0 = rowptr[node], e1 = rowptr[node + 1];
  float4 acc = make_float4(0.f, 0.f, 0.f, 0.f);
  for (int e = e0; e < e1; ++e) {
    int c = col[e];
    float4 v;
    if (IN_BF) {
      ushort4 u = reinterpret_cast<const ushort4*>(in)[(size_t)c * F4 + j];
      v = make_float4(bf2f(u.x), bf2f(u.y), bf2f(u.z), bf2f(u.w));
    } else {
      v = reinterpret_cast<const float4*>(in)[(size_t)c * F4 + j];
    }
    if (SCALE_SRC) {
      float sc = sSrc[c];
      v.x *= sc; v.y *= sc; v.z *= sc; v.w *= sc;
    }
    acc.x += v.x; acc.y += v.y; acc.z += v.z; acc.w += v.w;
  }
  if (EPI == 0) {
    if (OUT_BF) {
      ushort4 p;
      p.x = f2bf(acc.x); p.y = f2bf(acc.y); p.z = f2bf(acc.z); p.w = f2bf(acc.w);
      reinterpret_cast<ushort4*>(out)[(size_t)node * F4 + j] = p;
    } else {
      reinterpret_cast<float4*>(out)[(size_t)node * F4 + j] = acc;
    }
    return;
  }
  float sd = sDst[node];
  float4 bb = reinterpret_cast<const float4*>(bias)[j];
  acc.x = acc.x * sd + bb.x;
  acc.y = acc.y * sd + bb.y;
  acc.z = acc.z * sd + bb.z;
  acc.w = acc.w * sd + bb.w;
  if (EPI == 1) reinterpret_cast<float4*>(out)[(size_t)node * F4 + j] = acc;
  float4 o;
  o.x = 1.0f / (1.0f + expf(-acc.x));
  o.y = 1.0f / (1.0f + expf(-acc.y));
  o.z = 1.0f / (1.0f + expf(-acc.z));
  o.w = 1.0f / (1.0f + expf(-acc.w));
  reinterpret_cast<float4*>(out2)[(size_t)node * F4 + j] = o;
}

// ---------------- bf16 MFMA GEMM, LDS-free per-wave 64x64 tiles ----------------
// C[M,Npad] = epi(A[M,K] @ Bt[Npad,K]^T), K = NT_*32.
// One wave per block (64 threads). Fragments for mfma_f32_16x16x32_bf16 are 8
// contiguous bf16 at (row, k16*8) for BOTH A [M][K] and Bt [N][K] -> loaded
// directly global->VGPR (16 B/lane). No LDS, no barriers: latency hidden by
// occupancy (~96 VGPR -> 4 waves/SIMD) + per-wave ILP. Weights are L2-resident;
// bijective XCD swizzle (n-fastest) keeps A-row reuse within one XCD's L2.
// epi: v = acc*rowscale[r] + bias[c]; RELU; ZPAD: cols [Nreal,Npad) := 0.
template <int NT_, int OUT_BF, int RELU, int ZPAD>
__global__ __launch_bounds__(64, 4) void gemm3_kernel(
    const unsigned short* __restrict__ A, const unsigned short* __restrict__ Bt,
    void* __restrict__ C, int M, int Nreal, int Npad, int Mt, int Nt,
    const float* __restrict__ rowscale, const float* __restrict__ bias) {
  constexpr int K = NT_ * 32;
  const int T = gridDim.x;           // padded to multiple of 8
  const int chunk = T >> 3;
  const int bid = blockIdx.x;
  const int sw = (bid & 7) * chunk + (bid >> 3);  // bijective XCD chunking
  const int mt = sw / Nt, nt = sw - mt * Nt;      // n-fastest within chunk
  if (mt >= Mt) return;
  const int l = threadIdx.x;
  const int lrow = l & 15, k16 = l >> 4;
  const int m = mt * 64, n = nt * 64;
  const unsigned short* ap = A + (size_t)(m + lrow) * K + k16 * 8;
  const unsigned short* bp = Bt + (size_t)(n + lrow) * K + k16 * 8;

  f32x4 acc[4][4] = {};
  for (int t = 0; t < NT_; ++t) {
    bf16x8 a[4], b[4];
#pragma unroll
    for (int i = 0; i < 4; ++i)
      a[i] = *reinterpret_cast<const bf16x8*>(ap + (size_t)i * 16 * K + t * 32);
#pragma unroll
    for (int i = 0; i < 4; ++i)
      b[i] = *reinterpret_cast<const bf16x8*>(bp + (size_t)i * 16 * K + t * 32);
#pragma unroll
    for (int mi = 0; mi < 4; ++mi)
#pragma unroll
      for (int ni = 0; ni < 4; ++ni)
        acc[mi][ni] = __builtin_amdgcn_mfma_f32_16x16x32_bf16(a[mi], b[ni], acc[mi][ni], 0, 0, 0);
  }

  const int q4 = k16 * 4;
#pragma unroll
  for (int mi = 0; mi < 4; ++mi) {
#pragma unroll
    for (int q = 0; q < 4; ++q) {
      int r = m + mi * 16 + q4 + q;
      if (r >= M) continue;
      float rs = rowscale[r];
#pragma unroll
      for (int ni = 0; ni < 4; ++ni) {
        int c = n + ni * 16 + lrow;
        if (ZPAD && c >= Nreal) {
          ((unsigned short*)C)[(size_t)r * Npad + c] = 0;
          continue;
        }
        float v = acc[mi][ni][q] * rs;
        if (bias) v += bias[c];
        if (RELU) v = fmaxf(v, 0.f);
        if (OUT_BF) ((unsigned short*)C)[(size_t)r * Npad + c] = f2bf(v);
        else ((float*)C)[(size_t)r * Npad + c] = v;
      }
    }
  }
}

static inline int pad8(int t) { return (t + 7) & ~7; }

extern "C" void kernel_launch(void* const* d_in, const int* in_sizes, int n_in,
                              void* d_out, int out_size, void* d_ws, size_t ws_size,
                              hipStream_t stream) {
  const float* x  = (const float*)d_in[0];
  const int* src  = (const int*)d_in[1];
  const int* dst  = (const int*)d_in[2];
  const float* W1 = (const float*)d_in[3];
  const float* b1 = (const float*)d_in[4];
  const float* W2 = (const float*)d_in[5];
  const float* b2 = (const float*)d_in[6];
  const float* W3 = (const float*)d_in[7];
  const float* b3 = (const float*)d_in[8];
  const float* W4 = (const float*)d_in[9];
  const float* b4 = (const float*)d_in[10];

  float* out_enc = (float*)d_out;                  // [NN,128]
  float* out_dec = out_enc + (size_t)NN * 128;     // [NN,256]

  // ---- workspace layout (~85 MB, all chunks 16B multiples) ----
  float* ns = (float*)d_ws;                        // [NN]
  float* nd = ns + NN;                             // [NN]
  float* T2 = nd + NN;                             // [NN*128] f32 (GEMM2 out)
  float* h2 = T2 + (size_t)NN * 128;               // [NN*128] f32 (pre-sigmoid encoded)
  unsigned short* A1  = (unsigned short*)(h2 + (size_t)NN * 128); // [MPAD*256]
  unsigned short* A3  = A1 + (size_t)MPAD * 256;   // [MPAD*128]
  unsigned short* G4  = A3 + (size_t)MPAD * 128;   // [NN*256] bf16 (GEMM4 out)
  unsigned short* H1  = G4 + (size_t)NN * 256;     // [MPAD*896] (GEMM1/3 out, K-padded)
  unsigned short* W1t = H1 + (size_t)MPAD * 896;   // [896*256]
  unsigned short* W2t = W1t + 896 * 256;           // [128*896]
  unsigned short* W3t = W2t + 128 * 896;           // [896*128]
  unsigned short* W4t = W3t + 896 * 128;           // [256*896]
  int* degs   = (int*)(W4t + 256 * 896);           // [NN]
  int* degd   = degs + NN;                         // [NN]
  int* cursor = degd + NN;                         // [NN]
  int* rowptr = cursor + NN;                       // [NN+1]
  int* col    = rowptr + NN + 1;                   // [NE]

  // ---- CSR build + norms ----
  hipMemsetAsync(degs, 0, 3 * NN * sizeof(int), stream);
  deg_count_kernel<<<(NE + 255) / 256, 256, 0, stream>>>(src, dst, degs, degd, NE);
  norm_kernel<<<(NN + 255) / 256, 256, 0, stream>>>(degs, degd, ns, nd, NN);
  scan_kernel<<<1, 1024, 0, stream>>>(degd, rowptr, NN);
  csr_fill_kernel<<<(NE + 255) / 256, 256, 0, stream>>>(src, dst, rowptr, cursor, col, NE);

  // ---- weight conversion (transpose + pad + bf16): Wt[Npad][Kpad] ----
  wt_convert_kernel<<<dim3(1, 896), 256, 0, stream>>>(W1, W1t, 256, 800, 256);
  wt_convert_kernel<<<dim3(4, 128), 256, 0, stream>>>(W2, W2t, 800, 128, 896);
  wt_convert_kernel<<<dim3(1, 896), 256, 0, stream>>>(W3, W3t, 128, 800, 128);
  wt_convert_kernel<<<dim3(4, 256), 256, 0, stream>>>(W4, W4t, 800, 256, 896);

  const int Mt = MPAD / 64;  // 314

  // ---- L1: gather(x*ns) -> bf16 A1; GEMM1 (K=256 -> N 800/896) relu -> H1 ----
  gather_kernel<256, 1, 0, 1, 0><<<(NN + 3) / 4, 256, 0, stream>>>(
      x, ns, rowptr, col, nullptr, nullptr, A1, nullptr, NN);
  gemm3_kernel<8, 1, 1, 1><<<pad8(Mt * 14), 64, 0, stream>>>(
      A1, W1t, H1, NN, 800, 896, Mt, 14, nd, b1);

  // ---- L2: GEMM2 (K=896 -> 128)*ns -> f32 T2; gather -> h2 + sigmoid(out_enc) ----
  gemm3_kernel<28, 0, 0, 0><<<pad8(Mt * 2), 64, 0, stream>>>(
      H1, W2t, T2, NN, 128, 128, Mt, 2, ns, nullptr);
  gather_kernel<128, 0, 1, 0, 0><<<(NN + 7) / 8, 256, 0, stream>>>(
      T2, nullptr, rowptr, col, nd, b2, h2, out_enc, NN);

  // ---- L3: gather(h2*ns) -> bf16 A3; GEMM3 (K=128 -> 800/896) relu -> H1 ----
  gather_kernel<128, 1, 0, 1, 0><<<(NN + 7) / 8, 256, 0, stream>>>(
      h2, ns, rowptr, col, nullptr, nullptr, A3, nullptr, NN);
  gemm3_kernel<4, 1, 1, 1><<<pad8(Mt * 14), 64, 0, stream>>>(
      A3, W3t, H1, NN, 800, 896, Mt, 14, nd, b3);

  // ---- L4: GEMM4 (K=896 -> 256)*ns -> bf16 G4; gather -> sigmoid(out_dec) ----
  gemm3_kernel<28, 1, 0, 0><<<pad8(Mt * 4), 64, 0, stream>>>(
      H1, W4t, G4, NN, 256, 256, Mt, 4, ns, nullptr);
  gather_kernel<256, 0, 2, 0, 1><<<(NN + 3) / 4, 256, 0, stream>>>(
      G4, nullptr, rowptr, col, nd, b4, nullptr, out_dec, NN);
}

// Round 6
// 419.054 us; speedup vs baseline: 1.0199x; 1.0199x over previous
//
#include <hip/hip_runtime.h>
#include <math.h>

constexpr int NN = 20000;   // nodes
constexpr int NE = 320000;  // edges
constexpr int MPAD = 20096; // NN padded to 128 (=> multiple of 64)

typedef __bf16 bf16x8 __attribute__((ext_vector_type(8)));
typedef float f32x4 __attribute__((ext_vector_type(4)));

__device__ __forceinline__ unsigned short f2bf(float f) {
  unsigned int u = __float_as_uint(f);
  unsigned int r = (u + 0x7FFFu + ((u >> 16) & 1u)) >> 16;
  return (unsigned short)r;
}
__device__ __forceinline__ float bf2f(unsigned short s) {
  return __uint_as_float(((unsigned int)s) << 16);
}

// ---------------- degree count ----------------
__global__ void deg_count_kernel(const int* __restrict__ src, const int* __restrict__ dst,
                                 int* __restrict__ degs, int* __restrict__ degd, int nE) {
  int e = blockIdx.x * blockDim.x + threadIdx.x;
  if (e < nE) {
    atomicAdd(degs + src[e], 1);
    atomicAdd(degd + dst[e], 1);
  }
}

__global__ void norm_kernel(const int* __restrict__ degs, const int* __restrict__ degd,
                            float* __restrict__ ns, float* __restrict__ nd, int n) {
  int i = blockIdx.x * blockDim.x + threadIdx.x;
  if (i < n) {
    ns[i] = rsqrtf(fmaxf((float)degs[i], 1.0f));
    nd[i] = rsqrtf(fmaxf((float)degd[i], 1.0f));
  }
}

// ---------------- single-block exclusive scan -> rowptr ----------------
__global__ __launch_bounds__(1024) void scan_kernel(const int* __restrict__ deg,
                                                    int* __restrict__ rowptr, int n) {
  constexpr int T = 1024;
  const int ITEMS = (n + T - 1) / T;
  __shared__ int sums[T];
  int t = threadIdx.x;
  int base = t * ITEMS;
  int s = 0;
  for (int i = 0; i < ITEMS; ++i) {
    int idx = base + i;
    if (idx < n) s += deg[idx];
  }
  sums[t] = s;
  __syncthreads();
  for (int off = 1; off < T; off <<= 1) {
    int v = (t >= off) ? sums[t - off] : 0;
    __syncthreads();
    sums[t] += v;
    __syncthreads();
  }
  int ex = (t == 0) ? 0 : sums[t - 1];
  for (int i = 0; i < ITEMS; ++i) {
    int idx = base + i;
    if (idx < n) {
      rowptr[idx] = ex;
      ex += deg[idx];
    }
  }
  if (t == 0) rowptr[n] = sums[T - 1];
}

// ---------------- CSR fill ----------------
__global__ void csr_fill_kernel(const int* __restrict__ src, const int* __restrict__ dst,
                                const int* __restrict__ rowptr, int* __restrict__ cursor,
                                int* __restrict__ col, int nE) {
  int e = blockIdx.x * blockDim.x + threadIdx.x;
  if (e < nE) {
    int d = dst[e];
    int p = atomicAdd(cursor + d, 1);
    col[rowptr[d] + p] = src[e];
  }
}

// ---------------- weight convert: W[K][N] f32 -> Wt[Npad][Kpad] bf16 (zero pad) -------
__global__ void wt_convert_kernel(const float* __restrict__ W, unsigned short* __restrict__ Wt,
                                  int K, int N, int Kpad) {
  int k = blockIdx.x * 256 + threadIdx.x;
  int n = blockIdx.y;
  if (k >= Kpad) return;
  float v = (n < N && k < K) ? W[(size_t)k * N + n] : 0.f;
  Wt[(size_t)n * Kpad + k] = f2bf(v);
}

// ---------------- CSR gather aggregation ----------------
template <int F, int SCALE_SRC, int EPI, int OUT_BF, int IN_BF>
__global__ __launch_bounds__(256) void gather_kernel(
    const void* __restrict__ in, const float* __restrict__ sSrc,
    const int* __restrict__ rowptr, const int* __restrict__ col,
    const float* __restrict__ sDst, const float* __restrict__ bias,
    void* __restrict__ out, float* __restrict__ out2, int n) {
  constexpr int F4 = F / 4;
  constexpr int NPB = 256 / F4;
  int tid = threadIdx.x;
  int node = blockIdx.x * NPB + tid / F4;
  int j = tid % F4;
  if (node >= n) return;
  int e0 = rowptr[node], e1 = rowptr[node + 1];
  float4 acc = make_float4(0.f, 0.f, 0.f, 0.f);
  for (int e = e0; e < e1; ++e) {
    int c = col[e];
    float4 v;
    if (IN_BF) {
      ushort4 u = reinterpret_cast<const ushort4*>(in)[(size_t)c * F4 + j];
      v = make_float4(bf2f(u.x), bf2f(u.y), bf2f(u.z), bf2f(u.w));
    } else {
      v = reinterpret_cast<const float4*>(in)[(size_t)c * F4 + j];
    }
    if (SCALE_SRC) {
      float sc = sSrc[c];
      v.x *= sc; v.y *= sc; v.z *= sc; v.w *= sc;
    }
    acc.x += v.x; acc.y += v.y; acc.z += v.z; acc.w += v.w;
  }
  if (EPI == 0) {
    if (OUT_BF) {
      ushort4 p;
      p.x = f2bf(acc.x); p.y = f2bf(acc.y); p.z = f2bf(acc.z); p.w = f2bf(acc.w);
      reinterpret_cast<ushort4*>(out)[(size_t)node * F4 + j] = p;
    } else {
      reinterpret_cast<float4*>(out)[(size_t)node * F4 + j] = acc;
    }
    return;
  }
  float sd = sDst[node];
  float4 bb = reinterpret_cast<const float4*>(bias)[j];
  acc.x = acc.x * sd + bb.x;
  acc.y = acc.y * sd + bb.y;
  acc.z = acc.z * sd + bb.z;
  acc.w = acc.w * sd + bb.w;
  if (EPI == 1) reinterpret_cast<float4*>(out)[(size_t)node * F4 + j] = acc;
  float4 o;
  o.x = 1.0f / (1.0f + expf(-acc.x));
  o.y = 1.0f / (1.0f + expf(-acc.y));
  o.z = 1.0f / (1.0f + expf(-acc.z));
  o.w = 1.0f / (1.0f + expf(-acc.w));
  reinterpret_cast<float4*>(out2)[(size_t)node * F4 + j] = o;
}

// ---------------- bf16 MFMA GEMM, LDS-free K-loop + vectorized LDS-bounce epilogue ----
// C[M,Npad] = epi(A[M,K] @ Bt[Npad,K]^T), K = NT_*32, NT_ even.
// One wave per block; 2-deep register ping-pong prefetch (named sets, static idx).
// Epilogue: acc -> wave-private LDS (XOR swizzle slot^=row&(CPR-1)) -> ds_read_b128
// -> contiguous 16 B/lane row-major stores (fixes 2B-scalar-store bottleneck).
template <int NT_, int OUT_BF, int RELU, int ZPAD>
__global__ __launch_bounds__(64, 3) void gemm4_kernel(
    const unsigned short* __restrict__ A, const unsigned short* __restrict__ Bt,
    void* __restrict__ C, int M, int Nreal, int Npad, int Mt, int Nt,
    const float* __restrict__ rowscale, const float* __restrict__ bias) {
  static_assert(NT_ % 2 == 0, "NT_ must be even");
  constexpr int K = NT_ * 32;
  constexpr int EB = OUT_BF ? 2 : 4;
  constexpr int ROWB = 64 * EB;
  constexpr int CPR = ROWB / 16;
  constexpr int RPI = 64 / CPR;
  __shared__ __align__(16) char lds[64 * ROWB];

  const int T = gridDim.x;
  const int chunk = T >> 3;
  const int bid = blockIdx.x;
  const int sw = (bid & 7) * chunk + (bid >> 3);
  const int mt = sw / Nt, nt = sw - mt * Nt;
  if (mt >= Mt) return;
  const int l = threadIdx.x;
  const int lrow = l & 15, k16 = l >> 4;
  const int m = mt * 64, n = nt * 64;
  const unsigned short* ap = A + (size_t)(m + lrow) * K + k16 * 8;
  const unsigned short* bp = Bt + (size_t)(n + lrow) * K + k16 * 8;

  f32x4 acc[4][4] = {};
  bf16x8 aA[4], bA[4], aB[4], bB[4];

#pragma unroll
  for (int i = 0; i < 4; ++i) {
    aA[i] = *reinterpret_cast<const bf16x8*>(ap + (size_t)i * 16 * K);
    bA[i] = *reinterpret_cast<const bf16x8*>(bp + (size_t)i * 16 * K);
  }
#pragma unroll
  for (int tt = 0; tt < NT_ / 2; ++tt) {
    const int t0 = 2 * tt;
    // prefetch t0+1 into set B
#pragma unroll
    for (int i = 0; i < 4; ++i) {
      aB[i] = *reinterpret_cast<const bf16x8*>(ap + (size_t)i * 16 * K + (t0 + 1) * 32);
      bB[i] = *reinterpret_cast<const bf16x8*>(bp + (size_t)i * 16 * K + (t0 + 1) * 32);
    }
    // compute set A (t0)
#pragma unroll
    for (int mi = 0; mi < 4; ++mi)
#pragma unroll
      for (int ni = 0; ni < 4; ++ni)
        acc[mi][ni] = __builtin_amdgcn_mfma_f32_16x16x32_bf16(aA[mi], bA[ni], acc[mi][ni], 0, 0, 0);
    // prefetch t0+2 into set A (if any)
    if (t0 + 2 < NT_) {
#pragma unroll
      for (int i = 0; i < 4; ++i) {
        aA[i] = *reinterpret_cast<const bf16x8*>(ap + (size_t)i * 16 * K + (t0 + 2) * 32);
        bA[i] = *reinterpret_cast<const bf16x8*>(bp + (size_t)i * 16 * K + (t0 + 2) * 32);
      }
    }
    // compute set B (t0+1)
#pragma unroll
    for (int mi = 0; mi < 4; ++mi)
#pragma unroll
      for (int ni = 0; ni < 4; ++ni)
        acc[mi][ni] = __builtin_amdgcn_mfma_f32_16x16x32_bf16(aB[mi], bB[ni], acc[mi][ni], 0, 0, 0);
  }

  // ---- epilogue: acc -> LDS (swizzled) ----
  const int q4 = k16 * 4;
#pragma unroll
  for (int mi = 0; mi < 4; ++mi) {
#pragma unroll
    for (int q = 0; q < 4; ++q) {
      int row = mi * 16 + q4 + q;
      int r = m + row;
      float rs = (r < M) ? rowscale[r] : 0.f;
#pragma unroll
      for (int ni = 0; ni < 4; ++ni) {
        int col = ni * 16 + lrow;
        int c = n + col;
        float v;
        if (ZPAD && c >= Nreal) {
          v = 0.f;
        } else {
          v = acc[mi][ni][q] * rs;
          if (bias) v += bias[c];
          if (RELU) v = fmaxf(v, 0.f);
        }
        int chnk = (col * EB) >> 4;
        int within = (col * EB) & 15;
        int addr = row * ROWB + ((chnk ^ (row & (CPR - 1))) << 4) + within;
        if (OUT_BF) *(unsigned short*)(lds + addr) = f2bf(v);
        else *(float*)(lds + addr) = v;
      }
    }
  }
  __syncthreads();

  // ---- LDS -> global, 16 B/lane contiguous row chunks ----
  const int lane_c = l % CPR;
  const int row0 = l / CPR;
#pragma unroll
  for (int j = 0; j < CPR; ++j) {
    int row = j * RPI + row0;
    int r = m + row;
    int addr = row * ROWB + ((lane_c ^ (row & (CPR - 1))) << 4);
    float4 v = *(const float4*)(lds + addr);
    if (r < M) {
      char* dstp = (char*)C + (size_t)r * Npad * EB + (size_t)n * EB + lane_c * 16;
      *(float4*)dstp = v;
    }
  }
}

static inline int pad8(int t) { return (t + 7) & ~7; }

extern "C" void kernel_launch(void* const* d_in, const int* in_sizes, int n_in,
                              void* d_out, int out_size, void* d_ws, size_t ws_size,
                              hipStream_t stream) {
  const float* x  = (const float*)d_in[0];
  const int* src  = (const int*)d_in[1];
  const int* dst  = (const int*)d_in[2];
  const float* W1 = (const float*)d_in[3];
  const float* b1 = (const float*)d_in[4];
  const float* W2 = (const float*)d_in[5];
  const float* b2 = (const float*)d_in[6];
  const float* W3 = (const float*)d_in[7];
  const float* b3 = (const float*)d_in[8];
  const float* W4 = (const float*)d_in[9];
  const float* b4 = (const float*)d_in[10];

  float* out_enc = (float*)d_out;                  // [NN,128]
  float* out_dec = out_enc + (size_t)NN * 128;     // [NN,256]

  // ---- workspace layout ----
  float* ns = (float*)d_ws;                        // [NN]
  float* nd = ns + NN;                             // [NN]
  float* T2 = nd + NN;                             // [NN*128] f32
  float* h2 = T2 + (size_t)NN * 128;               // [NN*128] f32
  unsigned short* A1  = (unsigned short*)(h2 + (size_t)NN * 128); // [MPAD*256]
  unsigned short* A3  = A1 + (size_t)MPAD * 256;   // [MPAD*128]
  unsigned short* G4  = A3 + (size_t)MPAD * 128;   // [NN*256] bf16
  unsigned short* H1  = G4 + (size_t)NN * 256;     // [MPAD*896]
  unsigned short* W1t = H1 + (size_t)MPAD * 896;   // [896*256]
  unsigned short* W2t = W1t + 896 * 256;           // [128*896]
  unsigned short* W3t = W2t + 128 * 896;           // [896*128]
  unsigned short* W4t = W3t + 896 * 128;           // [256*896]
  int* degs   = (int*)(W4t + 256 * 896);           // [NN]
  int* degd   = degs + NN;                         // [NN]
  int* cursor = degd + NN;                         // [NN]
  int* rowptr = cursor + NN;                       // [NN+1]
  int* col    = rowptr + NN + 1;                   // [NE]

  hipMemsetAsync(degs, 0, 3 * NN * sizeof(int), stream);
  deg_count_kernel<<<(NE + 255) / 256, 256, 0, stream>>>(src, dst, degs, degd, NE);
  norm_kernel<<<(NN + 255) / 256, 256, 0, stream>>>(degs, degd, ns, nd, NN);
  scan_kernel<<<1, 1024, 0, stream>>>(degd, rowptr, NN);
  csr_fill_kernel<<<(NE + 255) / 256, 256, 0, stream>>>(src, dst, rowptr, cursor, col, NE);

  wt_convert_kernel<<<dim3(1, 896), 256, 0, stream>>>(W1, W1t, 256, 800, 256);
  wt_convert_kernel<<<dim3(4, 128), 256, 0, stream>>>(W2, W2t, 800, 128, 896);
  wt_convert_kernel<<<dim3(1, 896), 256, 0, stream>>>(W3, W3t, 128, 800, 128);
  wt_convert_kernel<<<dim3(4, 256), 256, 0, stream>>>(W4, W4t, 800, 256, 896);

  const int Mt = MPAD / 64;  // 314

  // ---- L1 ----
  gather_kernel<256, 1, 0, 1, 0><<<(NN + 3) / 4, 256, 0, stream>>>(
      x, ns, rowptr, col, nullptr, nullptr, A1, nullptr, NN);
  gemm4_kernel<8, 1, 1, 1><<<pad8(Mt * 14), 64, 0, stream>>>(
      A1, W1t, H1, NN, 800, 896, Mt, 14, nd, b1);

  // ---- L2 ----
  gemm4_kernel<28, 0, 0, 0><<<pad8(Mt * 2), 64, 0, stream>>>(
      H1, W2t, T2, NN, 128, 128, Mt, 2, ns, nullptr);
  gather_kernel<128, 0, 1, 0, 0><<<(NN + 7) / 8, 256, 0, stream>>>(
      T2, nullptr, rowptr, col, nd, b2, h2, out_enc, NN);

  // ---- L3 ----
  gather_kernel<128, 1, 0, 1, 0><<<(NN + 7) / 8, 256, 0, stream>>>(
      h2, ns, rowptr, col, nullptr, nullptr, A3, nullptr, NN);
  gemm4_kernel<4, 1, 1, 1><<<pad8(Mt * 14), 64, 0, stream>>>(
      A3, W3t, H1, NN, 800, 896, Mt, 14, nd, b3);

  // ---- L4 ----
  gemm4_kernel<28, 1, 0, 0><<<pad8(Mt * 4), 64, 0, stream>>>(
      H1, W4t, G4, NN, 256, 256, Mt, 4, ns, nullptr);
  gather_kernel<256, 0, 2, 0, 1><<<(NN + 3) / 4, 256, 0, stream>>>(
      G4, nullptr, rowptr, col, nd, b4, nullptr, out_dec, NN);
}